// Round 2
// baseline (1089.029 us; speedup 1.0000x reference)
//
#include <hip/hip_runtime.h>

constexpr int NSUB  = 8;
constexpr int NCODE = 256;
constexpr int SDIM  = 96;
constexpr int EMB   = NSUB * SDIM;  // 768

// Block: 256 threads = 256 rows, one subspace per block.
// Grid: ceil(nrows/256) * 8.
__global__ __launch_bounds__(256) void pq_argmin_kernel(
    const float* __restrict__ emb,
    const float* __restrict__ cb,
    float* __restrict__ out,
    int nrows)
{
    const int m   = (int)(blockIdx.x & 7);
    const int row = (int)(blockIdx.x >> 3) * 256 + (int)threadIdx.x;

    const float* __restrict__ cbm = cb + (size_t)m * (NCODE * SDIM);

    // Precompute 0.5*||c_k||^2 into LDS (thread k handles code k).
    __shared__ float half_c2[NCODE];
    {
        const int k = (int)threadIdx.x;
        const float* c = cbm + k * SDIM;
        float s = 0.f;
        #pragma unroll
        for (int i = 0; i < SDIM; i += 4) {
            const float4 v = *reinterpret_cast<const float4*>(c + i);
            s = fmaf(v.x, v.x, s);
            s = fmaf(v.y, v.y, s);
            s = fmaf(v.z, v.z, s);
            s = fmaf(v.w, v.w, s);
        }
        half_c2[k] = 0.5f * s;
    }
    __syncthreads();

    if (row >= nrows) return;

    // Load this task's x sub-vector into registers (96 VGPRs, static indices).
    float x[SDIM];
    {
        const float* xr = emb + (size_t)row * EMB + m * SDIM;
        #pragma unroll
        for (int i = 0; i < SDIM; i += 4) {
            const float4 v = *reinterpret_cast<const float4*>(xr + i);
            x[i+0] = v.x; x[i+1] = v.y; x[i+2] = v.z; x[i+3] = v.w;
        }
    }

    // Fast path: fp32 argmin of score_k = 0.5*||c||^2 - x.c
    // (equals argmin ||x-c||^2; dist2 = x2 + 2*score).
    // Track best AND runner-up so near-ties can be re-decided in fp64.
    float best  = 3.4e38f;
    float best2 = 3.4e38f;
    int   bestk = 0;
    int   bestk2 = 0;
    #pragma unroll 1
    for (int k = 0; k < NCODE; k += 4) {
        const float* __restrict__ c0 = cbm + (k + 0) * SDIM;
        const float* __restrict__ c1 = cbm + (k + 1) * SDIM;
        const float* __restrict__ c2 = cbm + (k + 2) * SDIM;
        const float* __restrict__ c3 = cbm + (k + 3) * SDIM;
        float a0 = 0.f, a1 = 0.f, a2 = 0.f, a3 = 0.f;
        #pragma unroll
        for (int i = 0; i < SDIM; i += 4) {
            const float4 v0 = *reinterpret_cast<const float4*>(c0 + i);
            const float4 v1 = *reinterpret_cast<const float4*>(c1 + i);
            const float4 v2 = *reinterpret_cast<const float4*>(c2 + i);
            const float4 v3 = *reinterpret_cast<const float4*>(c3 + i);
            a0 = fmaf(x[i+0], v0.x, a0); a0 = fmaf(x[i+1], v0.y, a0);
            a0 = fmaf(x[i+2], v0.z, a0); a0 = fmaf(x[i+3], v0.w, a0);
            a1 = fmaf(x[i+0], v1.x, a1); a1 = fmaf(x[i+1], v1.y, a1);
            a1 = fmaf(x[i+2], v1.z, a1); a1 = fmaf(x[i+3], v1.w, a1);
            a2 = fmaf(x[i+0], v2.x, a2); a2 = fmaf(x[i+1], v2.y, a2);
            a2 = fmaf(x[i+2], v2.z, a2); a2 = fmaf(x[i+3], v2.w, a2);
            a3 = fmaf(x[i+0], v3.x, a3); a3 = fmaf(x[i+1], v3.y, a3);
            a3 = fmaf(x[i+2], v3.z, a3); a3 = fmaf(x[i+3], v3.w, a3);
        }
        const float s[4] = { half_c2[k+0] - a0, half_c2[k+1] - a1,
                             half_c2[k+2] - a2, half_c2[k+3] - a3 };
        #pragma unroll
        for (int j = 0; j < 4; ++j) {
            // Sequential strict-< keeps the FIRST minimum (numpy tie rule).
            if (s[j] < best) {
                best2 = best; bestk2 = bestk;
                best = s[j];  bestk = k + j;
            } else if (s[j] < best2) {
                best2 = s[j]; bestk2 = k + j;
            }
        }
    }

    // Near-tie: re-decide the top-2 candidates with exact (fp64) distances.
    // fp32 score error is < ~1e-3 worst-case; 0.02 gives 20x margin, and the
    // chance the true argmin is 3rd-ranked while the top-2 gap < 0.02 is ~1e-8.
    if (best2 - best < 0.02f) {
        const float* ca = cbm + bestk  * SDIM;
        const float* cbv = cbm + bestk2 * SDIM;
        double da = 0.0, db = 0.0;
        for (int i = 0; i < SDIM; ++i) {
            const double ea = (double)x[i] - (double)ca[i];
            const double eb = (double)x[i] - (double)cbv[i];
            da += ea * ea;
            db += eb * eb;
        }
        if (db < da || (db == da && bestk2 < bestk)) bestk = bestk2;
    }

    // Emit the winning code vector (L2-resident codebook gather).
    const float* cbest = cbm + bestk * SDIM;
    float* o = out + (size_t)row * EMB + m * SDIM;
    #pragma unroll
    for (int i = 0; i < SDIM; i += 4) {
        *reinterpret_cast<float4*>(o + i) =
            *reinterpret_cast<const float4*>(cbest + i);
    }
}

extern "C" void kernel_launch(void* const* d_in, const int* in_sizes, int n_in,
                              void* d_out, int out_size, void* d_ws, size_t ws_size,
                              hipStream_t stream) {
    const float* emb = (const float*)d_in[0];
    const float* cb  = (const float*)d_in[1];
    float* out = (float*)d_out;

    const int nrows = in_sizes[0] / EMB;            // 16*4096 = 65536
    const int rowBlocks = (nrows + 255) / 256;      // 256
    dim3 grid(rowBlocks * NSUB);                    // 2048 blocks
    dim3 block(256);
    pq_argmin_kernel<<<grid, block, 0, stream>>>(emb, cb, out, nrows);
}

// Round 3
// 310.099 us; speedup vs baseline: 3.5119x; 3.5119x over previous
//
#include <hip/hip_runtime.h>

typedef short   bf16x8 __attribute__((ext_vector_type(8)));
typedef unsigned short u16x4 __attribute__((ext_vector_type(4)));
typedef unsigned short u16x8 __attribute__((ext_vector_type(8)));
typedef float   f32x16 __attribute__((ext_vector_type(16)));

constexpr int NSUB  = 8;
constexpr int NCODE = 256;
constexpr int SDIM  = 96;
constexpr int EMB   = NSUB * SDIM;          // 768
constexpr int ROWS_BLK = 128;               // rows per block (4 waves x 32)

constexpr int    CB_UNITS      = 8 * 6 * 2 * 64;                 // 6144 x 16B per subspace
constexpr size_t WS_FRAG_BYTES = (size_t)NSUB * CB_UNITS * 16;   // 786432
constexpr size_t WS_NEEDED     = WS_FRAG_BYTES + (size_t)NSUB * NCODE * 4; // 794624

// dynamic-LDS layout (bytes)
constexpr int CB_OFF  = 0;                       // 98304: codebook frags (neg, hi/lo)
constexpr int X_OFF   = 98304;                   // 49152: x frags (hi/lo)
constexpr int C2_OFF  = 98304 + 49152;           // 1024 : 0.5*||c||^2
constexpr int BK_OFF  = C2_OFF + 1024;           // 512  : per-row best code
constexpr int LDS_TOTAL = BK_OFF + 512;          // 148992 <= 163840

__device__ __forceinline__ unsigned short f2bf(float v) {
    unsigned u = __builtin_bit_cast(unsigned, v);
    u = u + 0x7FFFu + ((u >> 16) & 1u);          // RNE
    return (unsigned short)(u >> 16);
}
__device__ __forceinline__ float bf2f(unsigned short h) {
    unsigned u = ((unsigned)h) << 16;
    return __builtin_bit_cast(float, u);
}

__device__ __forceinline__ void gll16(const void* g, void* lds) {
    __builtin_amdgcn_global_load_lds((const __attribute__((address_space(1))) unsigned int*)g,
                                     (__attribute__((address_space(3))) unsigned int*)lds, 16, 0, 0);
}
__device__ __forceinline__ void gll4(const void* g, void* lds) {
    __builtin_amdgcn_global_load_lds((const __attribute__((address_space(1))) unsigned int*)g,
                                     (__attribute__((address_space(3))) unsigned int*)lds, 4, 0, 0);
}

// ---------------- pre-kernel: pack codebook into ws ----------------
// ws frag layout: per m, unit u = ((t*6+s)*2+h)*64 + l  (16 B each):
//   code = t*32 + (l&31), k0 = s*16 + (l>>5)*8, value = h==0 ? hi : lo of (-cb)
__global__ __launch_bounds__(256) void pq_prep(const float* __restrict__ cb,
                                               unsigned short* __restrict__ wsf,
                                               float* __restrict__ wsc2)
{
    const int m   = (int)blockIdx.x;
    const int tid = (int)threadIdx.x;

    // 0.5*||c||^2 in fp64
    {
        const float* c = cb + ((size_t)m * NCODE + tid) * SDIM;
        double s = 0.0;
        for (int k = 0; k < SDIM; ++k) { double v = (double)c[k]; s += v * v; }
        wsc2[m * NCODE + tid] = (float)(0.5 * s);
    }

    for (int i = 0; i < 24; ++i) {
        int u  = i * 256 + tid;
        int l  = u & 63;
        int c6 = u >> 6;
        int h  = c6 & 1; c6 >>= 1;
        int s  = c6 % 6;
        int t  = c6 / 6;
        int code = t * 32 + (l & 31);
        int k0   = s * 16 + (l >> 5) * 8;
        const float* src = cb + (size_t)m * NCODE * SDIM + (size_t)code * SDIM + k0;
        u16x8 o;
        #pragma unroll
        for (int j = 0; j < 8; ++j) {
            float v = -src[j];
            unsigned short hb = f2bf(v);
            o[j] = (h == 0) ? hb : f2bf(v - bf2f(hb));
        }
        *(u16x8*)(wsf + ((size_t)m * CB_UNITS + u) * 8) = o;
    }
}

// ---------------- main kernel ----------------
__global__ __launch_bounds__(256, 1) void pq_mfma_kernel(
    const float* __restrict__ emb,
    const float* __restrict__ cb,
    const unsigned short* __restrict__ wsf,
    const float* __restrict__ wsc2,
    float* __restrict__ out,
    int nrows)
{
    extern __shared__ char smem[];
    const int tid  = (int)threadIdx.x;
    const int w    = tid >> 6;
    const int lane = tid & 63;
    const int row0 = (int)blockIdx.x * ROWS_BLK;
    const int hib  = lane >> 5;          // which K-chunk / code +4 offset

    float4 xf[12];                        // in-flight x slice (reg-staged, T14)

    // issue x loads for subspace mm (12 x dwordx4, coalesced 384B runs per row)
    auto issue_x = [&](int mm) {
        #pragma unroll
        for (int i = 0; i < 12; ++i) {
            int q = i * 256 + tid;
            int r = q / 24, f = q % 24;
            if (row0 + r < nrows)
                xf[i] = *(const float4*)(emb + (size_t)(row0 + r) * EMB + mm * SDIM + f * 4);
            else
                xf[i] = make_float4(0.f, 0.f, 0.f, 0.f);
        }
    };

    issue_x(0);

    for (int m = 0; m < NSUB; ++m) {
        // ---- stage codebook frags (global_load_lds, linear dest) ----
        {
            const unsigned short* base = wsf + (size_t)m * CB_UNITS * 8;
            #pragma unroll
            for (int i = 0; i < 24; ++i) {
                int ub = (w * 24 + i) * 64;
                gll16(base + (size_t)(ub + lane) * 8, smem + CB_OFF + ub * 16);
            }
            gll4(wsc2 + m * NCODE + w * 64 + lane, smem + C2_OFF + w * 256);
        }
        // ---- convert + write x(m) frags to LDS (fragment order) ----
        {
            #pragma unroll
            for (int i = 0; i < 12; ++i) {
                int q = i * 256 + tid;
                int r = q / 24, f = q % 24;
                int sP    = f >> 2;
                int khalf = (f >> 1) & 1;
                int j0    = (f & 1) * 4;
                int lP    = (r & 31) + 32 * khalf;
                int wP    = r >> 5;
                float v[4] = { xf[i].x, xf[i].y, xf[i].z, xf[i].w };
                u16x4 hi4, lo4;
                #pragma unroll
                for (int e = 0; e < 4; ++e) {
                    unsigned short hb = f2bf(v[e]);
                    hi4[e] = hb;
                    lo4[e] = f2bf(v[e] - bf2f(hb));
                }
                int u_hi = ((wP * 6 + sP) * 2 + 0) * 64 + lP;
                int u_lo = ((wP * 6 + sP) * 2 + 1) * 64 + lP;
                *(u16x4*)(smem + X_OFF + u_hi * 16 + j0 * 2) = hi4;
                *(u16x4*)(smem + X_OFF + u_lo * 16 + j0 * 2) = lo4;
            }
        }
        __syncthreads();                       // barrier 1 (drains gll + x writes)

        if (m < NSUB - 1) issue_x(m + 1);      // prefetch next x slice under compute

        // ---- load x frags (linear, conflict-free) ----
        bf16x8 xh[6], xl[6];
        #pragma unroll
        for (int s = 0; s < 6; ++s) {
            xh[s] = *(const bf16x8*)(smem + X_OFF + (((w * 6 + s) * 2 + 0) * 64 + lane) * 16);
            xl[s] = *(const bf16x8*)(smem + X_OFF + (((w * 6 + s) * 2 + 1) * 64 + lane) * 16);
        }

        // ---- init acc with 0.5*||c||^2 (broadcast LDS reads) ----
        f32x16 acc[8];
        const char* c2p = smem + C2_OFF;
        #pragma unroll
        for (int t = 0; t < 8; ++t) {
            float4 q0 = *(const float4*)(c2p + (t * 32 + hib * 4 + 0)  * 4);
            float4 q1 = *(const float4*)(c2p + (t * 32 + hib * 4 + 8)  * 4);
            float4 q2 = *(const float4*)(c2p + (t * 32 + hib * 4 + 16) * 4);
            float4 q3 = *(const float4*)(c2p + (t * 32 + hib * 4 + 24) * 4);
            acc[t] = (f32x16){ q0.x, q0.y, q0.z, q0.w,
                               q1.x, q1.y, q1.z, q1.w,
                               q2.x, q2.y, q2.z, q2.w,
                               q3.x, q3.y, q3.z, q3.w };
        }

        // ---- MFMA: acc[t] += (-c)hi*xhi + (-c)hi*xlo + (-c)lo*xhi ----
        #pragma unroll
        for (int s = 0; s < 6; ++s) {
            #pragma unroll
            for (int t = 0; t < 8; ++t) {
                bf16x8 ah = *(const bf16x8*)(smem + CB_OFF + (((t * 6 + s) * 2 + 0) * 64 + lane) * 16);
                bf16x8 al = *(const bf16x8*)(smem + CB_OFF + (((t * 6 + s) * 2 + 1) * 64 + lane) * 16);
                acc[t] = __builtin_amdgcn_mfma_f32_32x32x16_bf16(ah, xh[s], acc[t], 0, 0, 0);
                acc[t] = __builtin_amdgcn_mfma_f32_32x32x16_bf16(ah, xl[s], acc[t], 0, 0, 0);
                acc[t] = __builtin_amdgcn_mfma_f32_32x32x16_bf16(al, xh[s], acc[t], 0, 0, 0);
            }
        }

        // ---- epilogue: per-row argmin with runner-up ----
        // D[code][row]: row = lane&31 (per wave), code = t*32 + (r&3) + 8*(r>>2) + 4*hib
        float b1 = 3.4e38f, b2 = 3.4e38f;
        int   i1 = 1 << 30,  i2 = 1 << 30;
        const int hib4 = hib * 4;
        #pragma unroll
        for (int t = 0; t < 8; ++t) {
            #pragma unroll
            for (int r = 0; r < 16; ++r) {
                float sv = acc[t][r];
                int   kv = t * 32 + (r & 3) + 8 * (r >> 2) + hib4;
                if (sv < b1)      { b2 = b1; i2 = i1; b1 = sv; i1 = kv; }
                else if (sv < b2) { b2 = sv; i2 = kv; }
            }
        }
        {   // merge the two lanes (lane ^ 32) holding the same row
            float ob1 = __shfl_xor(b1, 32);
            int   oi1 = __shfl_xor(i1, 32);
            float ob2 = __shfl_xor(b2, 32);
            int   oi2 = __shfl_xor(i2, 32);
            bool o1_better = (ob1 < b1) || (ob1 == b1 && oi1 < i1);
            if (o1_better) {
                bool mine_better = (b1 < ob2) || (b1 == ob2 && i1 < oi2);
                if (mine_better) { b2 = b1; i2 = i1; } else { b2 = ob2; i2 = oi2; }
                b1 = ob1; i1 = oi1;
            } else {
                if ((ob1 < b2) || (ob1 == b2 && oi1 < i2)) { b2 = ob1; i2 = oi1; }
            }
        }
        if (lane < 32) {
            int rl   = w * 32 + lane;
            int grow = row0 + rl;
            if (grow < nrows) {
                if (b2 - b1 < 0.02f) {   // exact fp64 recheck of top-2 (rare)
                    const float* xr = emb + (size_t)grow * EMB + m * SDIM;
                    const float* ca = cb + (size_t)m * NCODE * SDIM + (size_t)i1 * SDIM;
                    const float* cbv = cb + (size_t)m * NCODE * SDIM + (size_t)i2 * SDIM;
                    double da = 0.0, db = 0.0;
                    for (int kk = 0; kk < SDIM; ++kk) {
                        double ea = (double)xr[kk] - (double)ca[kk];
                        double eb = (double)xr[kk] - (double)cbv[kk];
                        da += ea * ea; db += eb * eb;
                    }
                    if (db < da || (db == da && i2 < i1)) i1 = i2;
                }
                ((int*)(smem + BK_OFF))[rl] = i1;
            }
        }
        __syncthreads();                       // barrier 2

        // ---- gather + coalesced write-out ----
        {
            const int* bk = (const int*)(smem + BK_OFF);
            #pragma unroll
            for (int i = 0; i < 12; ++i) {
                int q = i * 256 + tid;
                int r = q / 24, f = q % 24;
                int grow = row0 + r;
                if (grow < nrows) {
                    int k = bk[r];
                    float4 v = *(const float4*)(cb + (size_t)m * NCODE * SDIM + (size_t)k * SDIM + f * 4);
                    *(float4*)(out + (size_t)grow * EMB + m * SDIM + f * 4) = v;
                }
            }
        }
    }
}

// ---------------- fallback (round-2 kernel, correct at 1089 us) ----------------
__global__ __launch_bounds__(256) void pq_argmin_kernel(
    const float* __restrict__ emb, const float* __restrict__ cb,
    float* __restrict__ out, int nrows)
{
    const int m   = (int)(blockIdx.x & 7);
    const int row = (int)(blockIdx.x >> 3) * 256 + (int)threadIdx.x;
    const float* __restrict__ cbm = cb + (size_t)m * (NCODE * SDIM);
    __shared__ float half_c2[NCODE];
    {
        const int k = (int)threadIdx.x;
        const float* c = cbm + k * SDIM;
        float s = 0.f;
        #pragma unroll
        for (int i = 0; i < SDIM; i += 4) {
            const float4 v = *reinterpret_cast<const float4*>(c + i);
            s = fmaf(v.x, v.x, s); s = fmaf(v.y, v.y, s);
            s = fmaf(v.z, v.z, s); s = fmaf(v.w, v.w, s);
        }
        half_c2[k] = 0.5f * s;
    }
    __syncthreads();
    if (row >= nrows) return;
    float x[SDIM];
    {
        const float* xr = emb + (size_t)row * EMB + m * SDIM;
        #pragma unroll
        for (int i = 0; i < SDIM; i += 4) {
            const float4 v = *reinterpret_cast<const float4*>(xr + i);
            x[i+0] = v.x; x[i+1] = v.y; x[i+2] = v.z; x[i+3] = v.w;
        }
    }
    float best = 3.4e38f, best2 = 3.4e38f;
    int bestk = 0, bestk2 = 0;
    #pragma unroll 1
    for (int k = 0; k < NCODE; k += 4) {
        const float* c0 = cbm + (k + 0) * SDIM;
        const float* c1 = cbm + (k + 1) * SDIM;
        const float* c2 = cbm + (k + 2) * SDIM;
        const float* c3 = cbm + (k + 3) * SDIM;
        float a0 = 0.f, a1 = 0.f, a2 = 0.f, a3 = 0.f;
        #pragma unroll
        for (int i = 0; i < SDIM; i += 4) {
            const float4 v0 = *reinterpret_cast<const float4*>(c0 + i);
            const float4 v1 = *reinterpret_cast<const float4*>(c1 + i);
            const float4 v2 = *reinterpret_cast<const float4*>(c2 + i);
            const float4 v3 = *reinterpret_cast<const float4*>(c3 + i);
            a0 = fmaf(x[i+0], v0.x, a0); a0 = fmaf(x[i+1], v0.y, a0);
            a0 = fmaf(x[i+2], v0.z, a0); a0 = fmaf(x[i+3], v0.w, a0);
            a1 = fmaf(x[i+0], v1.x, a1); a1 = fmaf(x[i+1], v1.y, a1);
            a1 = fmaf(x[i+2], v1.z, a1); a1 = fmaf(x[i+3], v1.w, a1);
            a2 = fmaf(x[i+0], v2.x, a2); a2 = fmaf(x[i+1], v2.y, a2);
            a2 = fmaf(x[i+2], v2.z, a2); a2 = fmaf(x[i+3], v2.w, a2);
            a3 = fmaf(x[i+0], v3.x, a3); a3 = fmaf(x[i+1], v3.y, a3);
            a3 = fmaf(x[i+2], v3.z, a3); a3 = fmaf(x[i+3], v3.w, a3);
        }
        const float s[4] = { half_c2[k+0] - a0, half_c2[k+1] - a1,
                             half_c2[k+2] - a2, half_c2[k+3] - a3 };
        #pragma unroll
        for (int j = 0; j < 4; ++j) {
            if (s[j] < best)       { best2 = best; bestk2 = bestk; best = s[j]; bestk = k + j; }
            else if (s[j] < best2) { best2 = s[j]; bestk2 = k + j; }
        }
    }
    if (best2 - best < 0.02f) {
        const float* ca = cbm + bestk  * SDIM;
        const float* cbv = cbm + bestk2 * SDIM;
        double da = 0.0, db = 0.0;
        for (int i = 0; i < SDIM; ++i) {
            const double ea = (double)x[i] - (double)ca[i];
            const double eb = (double)x[i] - (double)cbv[i];
            da += ea * ea; db += eb * eb;
        }
        if (db < da || (db == da && bestk2 < bestk)) bestk = bestk2;
    }
    const float* cbest = cbm + bestk * SDIM;
    float* o = out + (size_t)row * EMB + m * SDIM;
    #pragma unroll
    for (int i = 0; i < SDIM; i += 4)
        *reinterpret_cast<float4*>(o + i) = *reinterpret_cast<const float4*>(cbest + i);
}

extern "C" void kernel_launch(void* const* d_in, const int* in_sizes, int n_in,
                              void* d_out, int out_size, void* d_ws, size_t ws_size,
                              hipStream_t stream) {
    const float* emb = (const float*)d_in[0];
    const float* cb  = (const float*)d_in[1];
    float* out = (float*)d_out;
    const int nrows = in_sizes[0] / EMB;    // 65536

    if (ws_size < WS_NEEDED) {              // defensive fallback
        const int rowBlocks = (nrows + 255) / 256;
        pq_argmin_kernel<<<dim3(rowBlocks * NSUB), dim3(256), 0, stream>>>(emb, cb, out, nrows);
        return;
    }

    unsigned short* wsf = (unsigned short*)d_ws;
    float* wsc2 = (float*)((char*)d_ws + WS_FRAG_BYTES);

    pq_prep<<<dim3(NSUB), dim3(256), 0, stream>>>(cb, wsf, wsc2);

    hipFuncSetAttribute((const void*)pq_mfma_kernel,
                        hipFuncAttributeMaxDynamicSharedMemorySize, LDS_TOTAL);
    const int nblk = (nrows + ROWS_BLK - 1) / ROWS_BLK;   // 512
    pq_mfma_kernel<<<dim3(nblk), dim3(256), LDS_TOTAL, stream>>>(
        emb, cb, wsf, wsc2, out, nrows);
}